// Round 1
// baseline (18359.192 us; speedup 1.0000x reference)
//
#include <hip/hip_runtime.h>
#include <hip/hip_bf16.h>
#include <cstdint>
#include <cstddef>

// ---------------------------------------------------------------------------
// CustomLSTM: 2-layer LSTM, SEQ=512, B=64, IN=HS=1024.
// Round 1: correctness-first baseline.
//   - bf16 MFMA (16x16x32) GEMM per timestep, fp32 accumulate + fp32 cell.
//   - Weights pre-swizzled into B-fragment order (one-time-per-call prep).
//   - 1024 per-step kernel launches (graph nodes); kernel boundary = barrier.
// ---------------------------------------------------------------------------

typedef __attribute__((ext_vector_type(8))) short short8;     // 8 x bf16 (4 VGPRs)
typedef __attribute__((ext_vector_type(4))) float floatx4;    // MFMA accumulator

#define SEQL  512
#define BATCH 64
#define HSZ   1024
#define KTOT  2048           // [x | h] concatenated K
#define STEP_ELEMS 65536     // 64*1024, one timestep's h/x slab

// ---- workspace layout (bytes) ---------------------------------------------
// Wfrag  : 2 layers * 4096 * 2048 bf16 (fragment-ordered)  = 33,554,432
// xbf    : 512*64*1024 bf16                                = 67,108,864
// out0   : 512*64*1024 bf16 (layer-0 h, = layer-1 input)   = 67,108,864
// hping  : 2 * 65536 bf16                                  =    262,144
// hzero  : 65536 bf16                                      =    131,072
// c      : 2 * 65536 fp32                                  =    524,288
// bias   : 2 * 4096 fp32                                   =     32,768
// total ≈ 169 MB
#define OFF_WFRAG  ((size_t)0)
#define OFF_XBF    ((size_t)33554432)
#define OFF_OUT0   ((size_t)100663296)
#define OFF_HPING  ((size_t)167772160)
#define OFF_HZERO  ((size_t)168034304)
#define OFF_C      ((size_t)168165376)
#define OFF_BIAS   ((size_t)168689664)

// ---------------------------------------------------------------------------
// prep_misc: zero c (both layers), zero hzero, fuse biases. 1024 x 256.
// ---------------------------------------------------------------------------
__global__ __launch_bounds__(256) void prep_misc(
    const float* __restrict__ bih0, const float* __restrict__ bhh0,
    const float* __restrict__ bih1, const float* __restrict__ bhh1,
    float* __restrict__ c_ws, __hip_bfloat16* __restrict__ hzero,
    float* __restrict__ bias)
{
    int idx = blockIdx.x * 256 + threadIdx.x;           // 0..262143
    if (idx < 131072) {
        c_ws[idx] = 0.f;
    } else if (idx < 196608) {
        hzero[idx - 131072] = __float2bfloat16(0.f);
    } else {
        int rr = idx - 196608;
        if (rr < 8192) {
            int l = rr >> 12;
            int n = rr & 4095;
            bias[l * 4096 + n] = l ? (bih1[n] + bhh1[n]) : (bih0[n] + bhh0[n]);
        }
    }
}

// ---------------------------------------------------------------------------
// prep_x: fp32 -> bf16 conversion of the input tensor. 32768 x 256, 4 elem/thr.
// ---------------------------------------------------------------------------
__global__ __launch_bounds__(256) void prep_x(
    const float* __restrict__ x, __hip_bfloat16* __restrict__ xbf)
{
    size_t i = ((size_t)blockIdx.x * 256 + threadIdx.x) * 4;
    float4 v = *(const float4*)(x + i);
    alignas(8) __hip_bfloat16 t[4];
    t[0] = __float2bfloat16(v.x);
    t[1] = __float2bfloat16(v.y);
    t[2] = __float2bfloat16(v.z);
    t[3] = __float2bfloat16(v.w);
    *(uint64_t*)(xbf + i) = *(const uint64_t*)t;
}

// ---------------------------------------------------------------------------
// prep_w: build fragment-ordered bf16 weights.
// Layout: [layer][block 64][kk 64][nt 4][lane 64] x 8 bf16, where for MFMA
// 16x16x32 B-operand: n = lane&15 (within N-tile), k = (lane>>4)*8 + j.
// Block b owns hidden units j0=b*16; N-tile nt is gate nt (i/f/g/o).
// W row = nt*1024 + b*16 + (lane&15); k<1024 -> U, else V (K = [x|h]).
// 8192 x 256 = 2,097,152 threads, one 16-B fragment entry each.
// ---------------------------------------------------------------------------
__global__ __launch_bounds__(256) void prep_w(
    const float* __restrict__ U0, const float* __restrict__ V0,
    const float* __restrict__ U1, const float* __restrict__ V1,
    short8* __restrict__ Wf)
{
    int idx = blockIdx.x * 256 + threadIdx.x;   // 0..2,097,151
    int lane = idx & 63;
    int r = idx >> 6;
    int nt = r & 3;  r >>= 2;
    int kk = r & 63; r >>= 6;
    int b  = r & 63;
    int layer = r >> 6;

    const float* U = layer ? U1 : U0;
    const float* V = layer ? V1 : V0;
    int wrow = nt * 1024 + b * 16 + (lane & 15);
    int k = kk * 32 + ((lane >> 4) * 8);
    const float* src = (k < 1024) ? (U + (size_t)wrow * 1024 + k)
                                  : (V + (size_t)wrow * 1024 + (k - 1024));
    float4 v0 = *(const float4*)(src);
    float4 v1 = *(const float4*)(src + 4);
    alignas(16) __hip_bfloat16 t[8];
    t[0] = __float2bfloat16(v0.x); t[1] = __float2bfloat16(v0.y);
    t[2] = __float2bfloat16(v0.z); t[3] = __float2bfloat16(v0.w);
    t[4] = __float2bfloat16(v1.x); t[5] = __float2bfloat16(v1.y);
    t[6] = __float2bfloat16(v1.z); t[7] = __float2bfloat16(v1.w);
    Wf[idx] = *(const short8*)t;
}

// ---------------------------------------------------------------------------
// lstm_step: one timestep of one layer.
// grid 64 blocks x 512 threads (8 waves). Block b -> 16 hidden units.
// gates[64, 16cols x 4 gates] = [x_t | h] @ Wcat^T, then fused LSTM cell.
// Waves: mt = w&3 (M-tile, 16 batch rows), npair = w>>2 (gates {0,1} or {2,3}).
// ---------------------------------------------------------------------------
__global__ __launch_bounds__(512) void lstm_step(
    const __hip_bfloat16* __restrict__ xpart,   // [64][1024] bf16 (layer input @ t)
    const __hip_bfloat16* __restrict__ hprev,   // [64][1024] bf16
    const short8* __restrict__ Wf,              // this layer's fragments
    const float* __restrict__ bias,             // [4096] fused bias
    float* __restrict__ c,                      // [64][1024] fp32, in/out
    __hip_bfloat16* __restrict__ hout_bf,       // [64][1024] bf16
    float* __restrict__ hout_f32,               // null or [64][1024] (out1 slice)
    float* __restrict__ hfin,                   // null unless t==511 (h_f slice)
    float* __restrict__ cfin)                   // null unless t==511 (c_f slice)
{
    __shared__ short Alds[64][264];             // 256-wide K chunk, +8 pad
    __shared__ float Glds[4][64][20];           // gates staging, +4 pad

    const int tid  = threadIdx.x;
    const int w    = tid >> 6;
    const int lane = tid & 63;
    const int mt    = w & 3;
    const int npair = w >> 2;                   // 0 -> gates 0,1 ; 1 -> gates 2,3
    const int arow  = mt * 16 + (lane & 15);
    const int acol  = (lane >> 4) * 8;

    floatx4 acc0 = {0.f, 0.f, 0.f, 0.f};
    floatx4 acc1 = {0.f, 0.f, 0.f, 0.f};

    const size_t wbase = (size_t)blockIdx.x * (64 * 4 * 64);  // frag entries/block

    for (int kc = 0; kc < 8; ++kc) {
        __syncthreads();                        // protect prior chunk's ds_reads
        const __hip_bfloat16* src =
            (kc < 4) ? (xpart + kc * 256) : (hprev + (kc - 4) * 256);
        #pragma unroll
        for (int u4 = 0; u4 < 4; ++u4) {
            int u = tid + u4 * 512;             // 0..2047 16-B units
            int row  = u >> 5;
            int col8 = (u & 31) * 8;
            float4 v = *(const float4*)(src + row * 1024 + col8);
            *(float4*)&Alds[row][col8] = v;
        }
        __syncthreads();
        #pragma unroll
        for (int kl = 0; kl < 8; ++kl) {
            const int kk = kc * 8 + kl;
            short8 a  = *(const short8*)&Alds[arow][kl * 32 + acol];
            short8 b0 = Wf[wbase + ((size_t)kk * 4 + npair * 2    ) * 64 + lane];
            short8 b1 = Wf[wbase + ((size_t)kk * 4 + npair * 2 + 1) * 64 + lane];
            acc0 = __builtin_amdgcn_mfma_f32_16x16x32_bf16(a, b0, acc0, 0, 0, 0);
            acc1 = __builtin_amdgcn_mfma_f32_16x16x32_bf16(a, b1, acc1, 0, 0, 0);
        }
    }

    // stage gates to LDS (C-layout: col = lane&15, row = (lane>>4)*4 + reg)
    {
        const int col = lane & 15;
        const int rq  = (lane >> 4) * 4;
        #pragma unroll
        for (int r = 0; r < 4; ++r) {
            Glds[npair * 2    ][mt * 16 + rq + r][col] = acc0[r];
            Glds[npair * 2 + 1][mt * 16 + rq + r][col] = acc1[r];
        }
    }
    __syncthreads();

    // fused LSTM cell: 1024 (row, j) items, 2 per thread
    #pragma unroll
    for (int s = 0; s < 2; ++s) {
        int item = tid + s * 512;
        int row = item >> 4;
        int jj  = item & 15;
        int j   = blockIdx.x * 16 + jj;
        float gi = Glds[0][row][jj] + bias[j];
        float gf = Glds[1][row][jj] + bias[HSZ + j];
        float gg = Glds[2][row][jj] + bias[2 * HSZ + j];
        float go = Glds[3][row][jj] + bias[3 * HSZ + j];
        float iv = 1.f / (1.f + __expf(-gi));
        float fv = 1.f / (1.f + __expf(-gf));
        float gv = tanhf(gg);
        float ov = 1.f / (1.f + __expf(-go));
        int cidx = row * HSZ + j;
        float cn = fv * c[cidx] + iv * gv;
        float hn = ov * tanhf(cn);
        c[cidx] = cn;
        hout_bf[cidx] = __float2bfloat16(hn);
        if (hout_f32) hout_f32[cidx] = hn;
        if (hfin) { hfin[cidx] = hn; cfin[cidx] = cn; }
    }
}

// ---------------------------------------------------------------------------
extern "C" void kernel_launch(void* const* d_in, const int* in_sizes, int n_in,
                              void* d_out, int out_size, void* d_ws, size_t ws_size,
                              hipStream_t stream)
{
    const float* x    = (const float*)d_in[0];
    const float* U0   = (const float*)d_in[1];
    const float* V0   = (const float*)d_in[2];
    const float* bih0 = (const float*)d_in[3];
    const float* bhh0 = (const float*)d_in[4];
    const float* U1   = (const float*)d_in[5];
    const float* V1   = (const float*)d_in[6];
    const float* bih1 = (const float*)d_in[7];
    const float* bhh1 = (const float*)d_in[8];
    float* out = (float*)d_out;

    char* ws = (char*)d_ws;
    short8*         Wf    = (short8*)(ws + OFF_WFRAG);
    __hip_bfloat16* xbf   = (__hip_bfloat16*)(ws + OFF_XBF);
    __hip_bfloat16* out0  = (__hip_bfloat16*)(ws + OFF_OUT0);
    __hip_bfloat16* hping = (__hip_bfloat16*)(ws + OFF_HPING);
    __hip_bfloat16* hzero = (__hip_bfloat16*)(ws + OFF_HZERO);
    float*          c_ws  = (float*)(ws + OFF_C);
    float*          bias  = (float*)(ws + OFF_BIAS);

    prep_misc<<<dim3(1024), dim3(256), 0, stream>>>(bih0, bhh0, bih1, bhh1,
                                                    c_ws, hzero, bias);
    prep_x<<<dim3(32768), dim3(256), 0, stream>>>(x, xbf);
    prep_w<<<dim3(8192), dim3(256), 0, stream>>>(U0, V0, U1, V1, Wf);

    float* out1 = out;                         // [512][64][1024]
    float* hf   = out + 33554432;              // [2][64][1024]
    float* cf   = out + 33554432 + 131072;     // [2][64][1024]

    const size_t WLAYER = (size_t)4096 * 2048 / 8;  // short8 entries per layer

    // layer 0: h history stored in out0 (bf16) = layer-1 input
    for (int t = 0; t < SEQL; ++t) {
        const __hip_bfloat16* xp = xbf + (size_t)t * STEP_ELEMS;
        const __hip_bfloat16* hp =
            t ? (out0 + (size_t)(t - 1) * STEP_ELEMS) : hzero;
        lstm_step<<<dim3(64), dim3(512), 0, stream>>>(
            xp, hp, Wf, bias, c_ws,
            out0 + (size_t)t * STEP_ELEMS, nullptr,
            (t == SEQL - 1) ? hf : nullptr,
            (t == SEQL - 1) ? cf : nullptr);
    }
    // layer 1: h ping-pong; fp32 h -> out1
    for (int t = 0; t < SEQL; ++t) {
        const __hip_bfloat16* xp = out0 + (size_t)t * STEP_ELEMS;
        const __hip_bfloat16* hp =
            t ? (hping + (size_t)((t - 1) & 1) * STEP_ELEMS) : hzero;
        lstm_step<<<dim3(64), dim3(512), 0, stream>>>(
            xp, hp, Wf + WLAYER, bias + 4096, c_ws + STEP_ELEMS,
            hping + (size_t)(t & 1) * STEP_ELEMS,
            out1 + (size_t)t * STEP_ELEMS,
            (t == SEQL - 1) ? hf + STEP_ELEMS : nullptr,
            (t == SEQL - 1) ? cf + STEP_ELEMS : nullptr);
    }
}